// Round 3
// baseline (412.982 us; speedup 1.0000x reference)
//
#include <hip/hip_runtime.h>
#include <hip/hip_bf16.h>
#include <stdint.h>

// PointNet EdgeConv, 2 layers. Round 18.
// R10: atomic-free bucket sort + MFMA edge_seg.                278 us
// R14: cvt_pk_bf16 + bf16 m-matrix + bias-in-C.                233 us
// R15: fused setup; 512-edge edge_seg blocks.                  230 us <- best
// R16: direct-to-fragment gathers in edge_seg.                 237 us
// R17: range-bucket edge kernel (kernels deleted, exclusive     252 us
//      writeout) — but edge_range is gather-LATENCY-bound:
//      MfmaUtil 2.2%, VALU 25%, HBM 22%, Occ 40%. 782 blocks x 4
//      serial chunks = too little TLP/MLP.
// R18: same structure, restore latency hiding:
//      * 1024-thread blocks (16 waves): nch 4->2, 2 blk/CU = 32 waves/CU
//      * wave-granular chunk skip (tail chunks ~1/16 cost; fixes M=0)
//      * sedgeB prefetched one chunk ahead (one fewer serial round-trip)

#define BS 256
#define EBS 1024       // edge kernel block size / chunk (1024 edges)
#define K1_EDGES 4096  // edges staged per block in scatter pass

typedef float v2f __attribute__((ext_vector_type(2)));
typedef __attribute__((ext_vector_type(8))) short bf16x8;
typedef __attribute__((ext_vector_type(16))) float f32x16;
typedef __bf16 bf16v2 __attribute__((ext_vector_type(2)));

__device__ __forceinline__ unsigned ordenc(float f) {
    unsigned u = __float_as_uint(f);
    return (u & 0x80000000u) ? ~u : (u | 0x80000000u);
}
__device__ __forceinline__ float orddec(unsigned o) {
    unsigned u = (o & 0x80000000u) ? (o ^ 0x80000000u) : ~o;
    return __uint_as_float(u);
}
#define ORD_NEG_INF 0x007FFFFFu  // ordenc(-inf)

// two f32 -> packed bf16 pair (RNE) via v_cvt_pk_bf16_f32; x -> low half
__device__ __forceinline__ unsigned cvt2(float x, float y) {
    v2f v = {x, y};
    bf16v2 b = __builtin_convertvector(v, bf16v2);
    return __builtin_bit_cast(unsigned, b);
}
__device__ __forceinline__ float bflo(unsigned u) { return __uint_as_float(u << 16); }
__device__ __forceinline__ float bfhi(unsigned u) { return __uint_as_float(u & 0xFFFF0000u); }

// build 8 channels of h = relu(bf16(U) - V) as 4 packed bf16 pairs
__device__ __forceinline__ uint4 mk_frag(uint4 ua, float4 v0, float4 v1) {
    uint4 o;
    o.x = cvt2(fmaxf(bflo(ua.x) - v0.x, 0.0f), fmaxf(bfhi(ua.x) - v0.y, 0.0f));
    o.y = cvt2(fmaxf(bflo(ua.y) - v0.z, 0.0f), fmaxf(bfhi(ua.y) - v0.w, 0.0f));
    o.z = cvt2(fmaxf(bflo(ua.z) - v1.x, 0.0f), fmaxf(bfhi(ua.z) - v1.y, 0.0f));
    o.w = cvt2(fmaxf(bflo(ua.w) - v1.z, 0.0f), fmaxf(bfhi(ua.w) - v1.w, 0.0f));
    return o;
}

// ---------------- fused setup: range-hist | prep1 | Wbt pack ----------------
__global__ __launch_bounds__(BS) void setup_kernel(
    const int* __restrict__ ei, int E, int NRP, int* __restrict__ blockHist,
    const float* __restrict__ pos, const float* __restrict__ Wa, const float* __restrict__ ba,
    unsigned* __restrict__ Ubf, float* __restrict__ V, int N, int NB1, int NBn,
    const float* __restrict__ Wb2, const float* __restrict__ Wb4,
    unsigned* __restrict__ WbtG) {
    __shared__ int hist[1024];
    const int tid = threadIdx.x;
    const int b = blockIdx.x;
    if (b < NB1) {
        for (int r = tid; r < 1024; r += BS) hist[r] = 0;
        __syncthreads();
        const int base = b * K1_EDGES;
        const int M = min(K1_EDGES, E - base);
        for (int i = tid; i < M; i += BS) atomicAdd(&hist[ei[E + base + i] >> 7], 1);
        __syncthreads();
        for (int r = tid; r < NRP; r += BS) blockHist[b * NRP + r] = hist[r];
    } else if (b < NB1 + NBn) {
        const int n = (b - NB1) * BS + tid;
        if (n >= N) return;
        const float p[3] = {pos[3 * n], pos[3 * n + 1], pos[3 * n + 2]};
        v2f u[16], v[16];
#pragma unroll
        for (int g = 0; g < 16; ++g) {
            u[g] = *reinterpret_cast<const v2f*>(&ba[g * 2]);
            v2f z = {0.0f, 0.0f};
            v[g] = z;
        }
#pragma unroll
        for (int i = 0; i < 3; ++i) {
            const v2f f = {p[i], p[i]};
#pragma unroll
            for (int g = 0; g < 16; ++g) {
                const v2f wA = *reinterpret_cast<const v2f*>(&Wa[i * 32 + g * 2]);
                const v2f wB = *reinterpret_cast<const v2f*>(&Wa[(i + 3) * 32 + g * 2]);
                u[g] = __builtin_elementwise_fma(f, wA + wB, u[g]);
                v[g] = __builtin_elementwise_fma(f, wB, v[g]);
            }
        }
        uint4* Up = reinterpret_cast<uint4*>(Ubf + (size_t)n * 16);
        float4* Vp = reinterpret_cast<float4*>(V + (size_t)n * 32);
#pragma unroll
        for (int q = 0; q < 4; ++q) {
            uint4 o;
            o.x = cvt2(u[4 * q + 0].x, u[4 * q + 0].y);
            o.y = cvt2(u[4 * q + 1].x, u[4 * q + 1].y);
            o.z = cvt2(u[4 * q + 2].x, u[4 * q + 2].y);
            o.w = cvt2(u[4 * q + 3].x, u[4 * q + 3].y);
            Up[q] = o;
        }
#pragma unroll
        for (int q = 0; q < 8; ++q)
            Vp[q] = make_float4(v[2 * q].x, v[2 * q].y, v[2 * q + 1].x, v[2 * q + 1].y);
    } else {
        // pack per-lane B fragments (bf16 pairs) for both layers: 2 x 512 dw
        if (tid < 128) {
            const int layer = tid >> 6;
            const int t = tid & 63;
            const int lnp = t & 31;
            const int hp = t >> 5;
            const float* Wb = layer ? Wb4 : Wb2;
            unsigned* dst = WbtG + layer * 512 + t * 8;
#pragma unroll
            for (int q = 0; q < 4; ++q) {
                const int p = 4 * hp + q;
                dst[q] = cvt2(Wb[(2 * p) * 32 + lnp], Wb[(2 * p + 1) * 32 + lnp]);
                dst[4 + q] = cvt2(Wb[(2 * p + 16) * 32 + lnp], Wb[(2 * p + 17) * 32 + lnp]);
            }
        }
    }
}

// ---------------- pass 2a: per-(block,range) LOCAL prefixes + range totals --
__global__ __launch_bounds__(512) void off_scan_kernel(const int* __restrict__ blockHist,
                                                       int NB1, int NRP,
                                                       int* __restrict__ off,
                                                       int* __restrict__ total) {
    const int r = (blockIdx.x * 512 + threadIdx.x) >> 6;
    const int lane = threadIdx.x & 63;
    if (r >= NRP) return;
    int carry = 0;
    const int chunks = (NB1 + 63) / 64;
    for (int c = 0; c < chunks; ++c) {
        const int b = c * 64 + lane;
        const int v = (b < NB1) ? blockHist[b * NRP + r] : 0;
        int x = v;
#pragma unroll
        for (int d = 1; d < 64; d <<= 1) {
            int y = __shfl_up(x, d, 64);
            if (lane >= d) x += y;
        }
        if (b < NB1) off[b * NRP + r] = carry + (x - v);
        carry += __shfl(x, 63, 64);
    }
    if (lane == 0) total[r] = carry;
}

// ---------------- pass 2b: exclusive scan of totals -> rangeBase ------------
__global__ __launch_bounds__(1024) void range_scan_kernel(const int* __restrict__ total,
                                                          int NRP, int* __restrict__ rangeBase) {
    __shared__ int s[1024];
    const int t = threadIdx.x;
    const int v = (t < NRP) ? total[t] : 0;
    s[t] = v;
    __syncthreads();
    for (int off = 1; off < 1024; off <<= 1) {
        int add = (t >= off) ? s[t - off] : 0;
        __syncthreads();
        s[t] += add;
        __syncthreads();
    }
    if (t < NRP) rangeBase[t] = s[t] - v;
}

// ---------------- pass 1b: LDS-ranked scatter into range buckets ------------
__global__ __launch_bounds__(BS) void bucket_scatter_kernel(
    const int* __restrict__ ei, int E, int NRP, const int* __restrict__ off,
    const int* __restrict__ rangeBase, int2* __restrict__ sedgeB) {
    __shared__ int2 stage[K1_EDGES];          // 32 KB
    __shared__ unsigned short inv[K1_EDGES];  // 8 KB
    __shared__ int hist[1024], start[1024], cursor[1024];
    __shared__ int ts[BS];
    const int tid = threadIdx.x;
    for (int r = tid; r < 1024; r += BS) hist[r] = 0;
    __syncthreads();
    const int base = blockIdx.x * K1_EDGES;
    const int M = min(K1_EDGES, E - base);
    for (int i = tid; i < M; i += BS) {
        const int2 p = make_int2(ei[base + i], ei[E + base + i]);
        stage[i] = p;
        atomicAdd(&hist[p.y >> 7], 1);
    }
    __syncthreads();
    {
        const int i0 = tid * 4;
        const int l0 = hist[i0], l1 = hist[i0 + 1], l2 = hist[i0 + 2], l3 = hist[i0 + 3];
        const int tsum = l0 + l1 + l2 + l3;
        ts[tid] = tsum;
        __syncthreads();
        for (int off2 = 1; off2 < BS; off2 <<= 1) {
            int add = (tid >= off2) ? ts[tid - off2] : 0;
            __syncthreads();
            ts[tid] += add;
            __syncthreads();
        }
        const int texcl = ts[tid] - tsum;
        start[i0] = texcl;
        start[i0 + 1] = texcl + l0;
        start[i0 + 2] = texcl + l0 + l1;
        start[i0 + 3] = texcl + l0 + l1 + l2;
        cursor[i0] = start[i0];
        cursor[i0 + 1] = start[i0 + 1];
        cursor[i0 + 2] = start[i0 + 2];
        cursor[i0 + 3] = start[i0 + 3];
    }
    __syncthreads();
    for (int i = tid; i < M; i += BS) {
        const int pos = atomicAdd(&cursor[stage[i].y >> 7], 1);
        inv[pos] = (unsigned short)i;
    }
    __syncthreads();
    const int* offb = off + blockIdx.x * NRP;
    for (int j = tid; j < M; j += BS) {
        const int2 p = stage[inv[j]];
        const int r = p.y >> 7;
        sedgeB[rangeBase[r] + offb[r] + (j - start[r])] = p;  // contiguous runs
    }
}

// Layer 2 prep: reads layer-1 agg as plain float (already relu'd).
__global__ __launch_bounds__(BS) void prep2_kernel(const float* __restrict__ pos,
                                                   const float* __restrict__ aggA,
                                                   const float* __restrict__ Wa,
                                                   const float* __restrict__ ba,
                                                   unsigned* __restrict__ Ubf,
                                                   float* __restrict__ V, int N) {
    int n = blockIdx.x * BS + threadIdx.x;
    if (n >= N) return;
    float h[32];
    const float4* hp = reinterpret_cast<const float4*>(aggA + (size_t)n * 32);
#pragma unroll
    for (int q = 0; q < 8; ++q) {
        float4 t = hp[q];
        h[4 * q + 0] = t.x;
        h[4 * q + 1] = t.y;
        h[4 * q + 2] = t.z;
        h[4 * q + 3] = t.w;
    }
    const float p[3] = {pos[3 * n], pos[3 * n + 1], pos[3 * n + 2]};
    v2f u[16], v[16];
#pragma unroll
    for (int g = 0; g < 16; ++g) {
        u[g] = *reinterpret_cast<const v2f*>(&ba[g * 2]);
        v2f z = {0.0f, 0.0f};
        v[g] = z;
    }
#pragma unroll
    for (int i = 0; i < 32; ++i) {
        const v2f f = {h[i], h[i]};
#pragma unroll
        for (int g = 0; g < 16; ++g) {
            const v2f w = *reinterpret_cast<const v2f*>(&Wa[i * 32 + g * 2]);
            u[g] = __builtin_elementwise_fma(f, w, u[g]);
        }
    }
#pragma unroll
    for (int i = 0; i < 3; ++i) {
        const v2f f = {p[i], p[i]};
#pragma unroll
        for (int g = 0; g < 16; ++g) {
            const v2f w = *reinterpret_cast<const v2f*>(&Wa[(32 + i) * 32 + g * 2]);
            u[g] = __builtin_elementwise_fma(f, w, u[g]);
            v[g] = __builtin_elementwise_fma(f, w, v[g]);
        }
    }
    uint4* Up = reinterpret_cast<uint4*>(Ubf + (size_t)n * 16);
    float4* Vp = reinterpret_cast<float4*>(V + (size_t)n * 32);
#pragma unroll
    for (int q = 0; q < 4; ++q) {
        uint4 o;
        o.x = cvt2(u[4 * q + 0].x, u[4 * q + 0].y);
        o.y = cvt2(u[4 * q + 1].x, u[4 * q + 1].y);
        o.z = cvt2(u[4 * q + 2].x, u[4 * q + 2].y);
        o.w = cvt2(u[4 * q + 3].x, u[4 * q + 3].y);
        Up[q] = o;
    }
#pragma unroll
    for (int q = 0; q < 8; ++q)
        Vp[q] = make_float4(v[2 * q].x, v[2 * q].y, v[2 * q + 1].x, v[2 * q + 1].y);
}

// ---------------- range-bucket edge kernel (16 waves / 1024-edge chunks) ----
// One block per range of 128 dsts. Wave w handles chunk edges [64w, 64w+64);
// waves skip chunks entirely past M (cheap tails). sedgeB for chunk c+1 is
// prefetched during chunk c. LDS atomicMax into aggL[dstLocal][ch];
// exclusive relu'd-float writeout.
__global__ __launch_bounds__(EBS, 8) void edge_range_kernel(
    const unsigned* __restrict__ Ubf, const float4* __restrict__ V,
    const int2* __restrict__ sedgeB, const int* __restrict__ rangeBase,
    const int* __restrict__ total, const unsigned* __restrict__ WbtG,
    const float* __restrict__ bb, float* __restrict__ out, int N) {
    __shared__ unsigned aggL[4096];  // [128 dst][32 ch], 16 KB

    const int tid = threadIdx.x;
    const int r = blockIdx.x;
    const int base = rangeBase[r];
    const int M = total[r];
    const int last = M - 1;

    const int l = tid & 63;
    const int w = tid >> 6;  // 0..15: wave w owns chunk edges [64w, 64w+64)
    const int half = l >> 5;
    const int ln = l & 31;

#pragma unroll
    for (int i = 0; i < 4; ++i) aggL[tid + i * EBS] = ORD_NEG_INF;

    // B fragments: precomputed per-lane packed bf16 (L1-hot, 2 loads)
    const uint4 bu0 = *reinterpret_cast<const uint4*>(WbtG + l * 8);
    const uint4 bu1 = *reinterpret_cast<const uint4*>(WbtG + l * 8 + 4);
    const float bbn = bb[ln];
    __syncthreads();  // aggL init visible before any atomics

    const int nch = (M + EBS - 1) >> 10;
    int2 edA, edB;
    if (64 * w < M) {  // prologue: chunk-0 edge descriptors
        const int j0 = min(64 * w + ln, last);
        const int j1 = min(j0 + 32, last);
        edA = sedgeB[base + j0];
        edB = sedgeB[base + j1];
    }
    for (int c = 0; c < nch; ++c) {
        // prefetch next chunk's descriptors (wave-uniform participation)
        int2 nA, nB;
        const int ncb = (c + 1) << 10;
        const bool nextAct = (c + 1 < nch) && (ncb + 64 * w < M);
        if (nextAct) {
            const int j0 = min(ncb + 64 * w + ln, last);
            const int j1 = min(j0 + 32, last);
            nA = sedgeB[base + j0];
            nB = sedgeB[base + j1];
        }
        if ((c << 10) + 64 * w < M) {  // this wave active this chunk
            uint4 au00, au01, au10, au11;
            {
                const uint4* Up = reinterpret_cast<const uint4*>(Ubf + (size_t)edA.x * 16);
                const float4* Vp = V + (size_t)edA.y * 8;
                au00 = mk_frag(Up[half], Vp[2 * half], Vp[2 * half + 1]);
                au01 = mk_frag(Up[2 + half], Vp[4 + 2 * half], Vp[5 + 2 * half]);
            }
            {
                const uint4* Up = reinterpret_cast<const uint4*>(Ubf + (size_t)edB.x * 16);
                const float4* Vp = V + (size_t)edB.y * 8;
                au10 = mk_frag(Up[half], Vp[2 * half], Vp[2 * half + 1]);
                au11 = mk_frag(Up[2 + half], Vp[4 + 2 * half], Vp[5 + 2 * half]);
            }

            f32x16 c0, c1;
#pragma unroll
            for (int i = 0; i < 16; ++i) {
                c0[i] = bbn;
                c1[i] = bbn;
            }
            c0 = __builtin_amdgcn_mfma_f32_32x32x16_bf16(
                __builtin_bit_cast(bf16x8, au00), __builtin_bit_cast(bf16x8, bu0), c0, 0, 0, 0);
            c0 = __builtin_amdgcn_mfma_f32_32x32x16_bf16(
                __builtin_bit_cast(bf16x8, au01), __builtin_bit_cast(bf16x8, bu1), c0, 0, 0, 0);
            c1 = __builtin_amdgcn_mfma_f32_32x32x16_bf16(
                __builtin_bit_cast(bf16x8, au10), __builtin_bit_cast(bf16x8, bu0), c1, 0, 0, 0);
            c1 = __builtin_amdgcn_mfma_f32_32x32x16_bf16(
                __builtin_bit_cast(bf16x8, au11), __builtin_bit_cast(bf16x8, bu1), c1, 0, 0, 0);

            // scatter-max: C row rr <-> edge offset eo = (rr&3)+8(rr>>2)+4h,
            // edge eo of this wave (c0) / eo+32 (c1). dst via __shfl.
            // aggL addr (dl<<5)|ln: lanes of a half hit distinct banks.
#pragma unroll
            for (int rr = 0; rr < 16; ++rr) {
                const int eo = (rr & 3) + 8 * (rr >> 2) + 4 * half;
                const int d0 = __shfl(edA.y, eo, 64);
                const int d1 = __shfl(edB.y, eo, 64);
                atomicMax(&aggL[((d0 & 127) << 5) | ln], ordenc(c0[rr]));
                atomicMax(&aggL[((d1 & 127) << 5) | ln], ordenc(c1[rr]));
            }
        }
        edA = nA;  // garbage if !nextAct, but then unused next iter
        edB = nB;
    }
    __syncthreads();

    // exclusive writeout: 4096 values, 4 per thread, decode + relu -> float
    const int idx = tid * 4;
    const int node = (r << 7) + (idx >> 5);
    if (node < N) {
        float4 o;
        o.x = fmaxf(orddec(aggL[idx + 0]), 0.0f);
        o.y = fmaxf(orddec(aggL[idx + 1]), 0.0f);
        o.z = fmaxf(orddec(aggL[idx + 2]), 0.0f);
        o.w = fmaxf(orddec(aggL[idx + 3]), 0.0f);
        *reinterpret_cast<float4*>(out + (size_t)node * 32 + (idx & 31)) = o;
    }
}

extern "C" void kernel_launch(void* const* d_in, const int* in_sizes, int n_in,
                              void* d_out, int out_size, void* d_ws, size_t ws_size,
                              hipStream_t stream) {
    const float* pos = (const float*)d_in[0];
    const int* ei = (const int*)d_in[1];
    const float* W1 = (const float*)d_in[3];
    const float* b1 = (const float*)d_in[4];
    const float* W2 = (const float*)d_in[5];
    const float* b2 = (const float*)d_in[6];
    const float* W3 = (const float*)d_in[7];
    const float* b3 = (const float*)d_in[8];
    const float* W4 = (const float*)d_in[9];
    const float* b4 = (const float*)d_in[10];

    const int E = in_sizes[1] / 2;
    const int N = in_sizes[0] / 3;
    const int n32 = N * 32;
    const int NPAD = ((N + BS - 1) / BS) * BS;
    const int NR = (N + 127) / 128;         // ranges of 128 dsts
    const int NRP = ((NR + 15) / 16) * 16;  // padded (<= 1024)
    const int NB1 = (E + K1_EDGES - 1) / K1_EDGES;
    const int BH = NB1 * NRP;

    int* blockHist = (int*)d_ws;              // BH
    int* off = blockHist + BH;                // BH
    int* total = off + BH;                    // NRP
    int* rangeBase = total + NRP;             // NRP
    int2* sedgeB = (int2*)(rangeBase + NRP);  // E (range-grouped edges)
    float* aggA = (float*)(sedgeB + E);       // n32 (layer-1 h, relu'd float)
    unsigned* Ubf = (unsigned*)(aggA + n32);  // NPAD*16 (bf16-packed U)
    float* Vbuf = (float*)(Ubf + (size_t)NPAD * 16);  // n32
    unsigned* WbtG = (unsigned*)(Vbuf + n32);         // 1024 dw (2 layers x 512)

    const int NBn = (N + BS - 1) / BS;

    // fused: hist | prep1 | Wbt pack (mutually independent)
    setup_kernel<<<NB1 + NBn + 1, BS, 0, stream>>>(ei, E, NRP, blockHist, pos, W1, b1, Ubf,
                                                   Vbuf, N, NB1, NBn, W2, W4, WbtG);
    off_scan_kernel<<<(NRP * 64 + 511) / 512, 512, 0, stream>>>(blockHist, NB1, NRP, off,
                                                                total);
    range_scan_kernel<<<1, 1024, 0, stream>>>(total, NRP, rangeBase);
    bucket_scatter_kernel<<<NB1, BS, 0, stream>>>(ei, E, NRP, off, rangeBase, sedgeB);

    // --- layer 1 ---
    edge_range_kernel<<<NR, EBS, 0, stream>>>(Ubf, (const float4*)Vbuf, sedgeB, rangeBase,
                                              total, WbtG, b2, aggA, N);
    // --- layer 2 ---
    prep2_kernel<<<NBn, BS, 0, stream>>>(pos, aggA, W3, b3, Ubf, Vbuf, N);
    edge_range_kernel<<<NR, EBS, 0, stream>>>(Ubf, (const float4*)Vbuf, sedgeB, rangeBase,
                                              total, WbtG + 512, b4, (float*)d_out, N);
}

// Round 4
// 215.510 us; speedup vs baseline: 1.9163x; 1.9163x over previous
//
#include <hip/hip_runtime.h>
#include <hip/hip_bf16.h>
#include <stdint.h>

// PointNet EdgeConv, 2 layers. Round 19.
// R14: cvt_pk_bf16 + bf16 m-matrix + bias-in-C.                233 us
// R15: fused setup; 512-edge edge_seg blocks.                  230 us <- best
// R17: range-bucket edge kernel (4 kernels deleted).           252 us
//      edge_range gather-latency-bound: VALU 25%, Occ 40%.
// R18: 1024-thr blocks + launch_bounds(1024,8): VGPR capped    413 us
//      at 64 -> SPILLED (WRITE_SIZE 14->235 MB). Lesson: c0+c1
//      alone = 32 VGPRs; this kernel needs ~80.
// R19: spill fix + V-in-LDS.
//      * EBS=512, __launch_bounds__(512,6): 85-VGPR budget (R17 used 40)
//      * keep R18 wave-granular tail skip + descriptor prefetch
//      * stage block's V (128 contiguous rows, 16 KB) into LDS with
//        stride-9 float4 padding -> 8 of 12 global gathers per lane-chunk
//        become LDS reads; only the 4 random U gathers stay global.
//      LDS 16(agg)+18(V) = 34 KB -> 4 blk/CU x 8 waves.

#define BS 256
#define EBS 512        // edge kernel block size / chunk (512 edges)
#define K1_EDGES 4096  // edges staged per block in scatter pass

typedef float v2f __attribute__((ext_vector_type(2)));
typedef __attribute__((ext_vector_type(8))) short bf16x8;
typedef __attribute__((ext_vector_type(16))) float f32x16;
typedef __bf16 bf16v2 __attribute__((ext_vector_type(2)));

__device__ __forceinline__ unsigned ordenc(float f) {
    unsigned u = __float_as_uint(f);
    return (u & 0x80000000u) ? ~u : (u | 0x80000000u);
}
__device__ __forceinline__ float orddec(unsigned o) {
    unsigned u = (o & 0x80000000u) ? (o ^ 0x80000000u) : ~o;
    return __uint_as_float(u);
}
#define ORD_NEG_INF 0x007FFFFFu  // ordenc(-inf)

// two f32 -> packed bf16 pair (RNE) via v_cvt_pk_bf16_f32; x -> low half
__device__ __forceinline__ unsigned cvt2(float x, float y) {
    v2f v = {x, y};
    bf16v2 b = __builtin_convertvector(v, bf16v2);
    return __builtin_bit_cast(unsigned, b);
}
__device__ __forceinline__ float bflo(unsigned u) { return __uint_as_float(u << 16); }
__device__ __forceinline__ float bfhi(unsigned u) { return __uint_as_float(u & 0xFFFF0000u); }

// build 8 channels of h = relu(bf16(U) - V) as 4 packed bf16 pairs
__device__ __forceinline__ uint4 mk_frag(uint4 ua, float4 v0, float4 v1) {
    uint4 o;
    o.x = cvt2(fmaxf(bflo(ua.x) - v0.x, 0.0f), fmaxf(bfhi(ua.x) - v0.y, 0.0f));
    o.y = cvt2(fmaxf(bflo(ua.y) - v0.z, 0.0f), fmaxf(bfhi(ua.y) - v0.w, 0.0f));
    o.z = cvt2(fmaxf(bflo(ua.z) - v1.x, 0.0f), fmaxf(bfhi(ua.z) - v1.y, 0.0f));
    o.w = cvt2(fmaxf(bflo(ua.w) - v1.z, 0.0f), fmaxf(bfhi(ua.w) - v1.w, 0.0f));
    return o;
}

// ---------------- fused setup: range-hist | prep1 | Wbt pack ----------------
__global__ __launch_bounds__(BS) void setup_kernel(
    const int* __restrict__ ei, int E, int NRP, int* __restrict__ blockHist,
    const float* __restrict__ pos, const float* __restrict__ Wa, const float* __restrict__ ba,
    unsigned* __restrict__ Ubf, float* __restrict__ V, int N, int NB1, int NBn,
    const float* __restrict__ Wb2, const float* __restrict__ Wb4,
    unsigned* __restrict__ WbtG) {
    __shared__ int hist[1024];
    const int tid = threadIdx.x;
    const int b = blockIdx.x;
    if (b < NB1) {
        for (int r = tid; r < 1024; r += BS) hist[r] = 0;
        __syncthreads();
        const int base = b * K1_EDGES;
        const int M = min(K1_EDGES, E - base);
        for (int i = tid; i < M; i += BS) atomicAdd(&hist[ei[E + base + i] >> 7], 1);
        __syncthreads();
        for (int r = tid; r < NRP; r += BS) blockHist[b * NRP + r] = hist[r];
    } else if (b < NB1 + NBn) {
        const int n = (b - NB1) * BS + tid;
        if (n >= N) return;
        const float p[3] = {pos[3 * n], pos[3 * n + 1], pos[3 * n + 2]};
        v2f u[16], v[16];
#pragma unroll
        for (int g = 0; g < 16; ++g) {
            u[g] = *reinterpret_cast<const v2f*>(&ba[g * 2]);
            v2f z = {0.0f, 0.0f};
            v[g] = z;
        }
#pragma unroll
        for (int i = 0; i < 3; ++i) {
            const v2f f = {p[i], p[i]};
#pragma unroll
            for (int g = 0; g < 16; ++g) {
                const v2f wA = *reinterpret_cast<const v2f*>(&Wa[i * 32 + g * 2]);
                const v2f wB = *reinterpret_cast<const v2f*>(&Wa[(i + 3) * 32 + g * 2]);
                u[g] = __builtin_elementwise_fma(f, wA + wB, u[g]);
                v[g] = __builtin_elementwise_fma(f, wB, v[g]);
            }
        }
        uint4* Up = reinterpret_cast<uint4*>(Ubf + (size_t)n * 16);
        float4* Vp = reinterpret_cast<float4*>(V + (size_t)n * 32);
#pragma unroll
        for (int q = 0; q < 4; ++q) {
            uint4 o;
            o.x = cvt2(u[4 * q + 0].x, u[4 * q + 0].y);
            o.y = cvt2(u[4 * q + 1].x, u[4 * q + 1].y);
            o.z = cvt2(u[4 * q + 2].x, u[4 * q + 2].y);
            o.w = cvt2(u[4 * q + 3].x, u[4 * q + 3].y);
            Up[q] = o;
        }
#pragma unroll
        for (int q = 0; q < 8; ++q)
            Vp[q] = make_float4(v[2 * q].x, v[2 * q].y, v[2 * q + 1].x, v[2 * q + 1].y);
    } else {
        // pack per-lane B fragments (bf16 pairs) for both layers: 2 x 512 dw
        if (tid < 128) {
            const int layer = tid >> 6;
            const int t = tid & 63;
            const int lnp = t & 31;
            const int hp = t >> 5;
            const float* Wb = layer ? Wb4 : Wb2;
            unsigned* dst = WbtG + layer * 512 + t * 8;
#pragma unroll
            for (int q = 0; q < 4; ++q) {
                const int p = 4 * hp + q;
                dst[q] = cvt2(Wb[(2 * p) * 32 + lnp], Wb[(2 * p + 1) * 32 + lnp]);
                dst[4 + q] = cvt2(Wb[(2 * p + 16) * 32 + lnp], Wb[(2 * p + 17) * 32 + lnp]);
            }
        }
    }
}

// ---------------- pass 2a: per-(block,range) LOCAL prefixes + range totals --
__global__ __launch_bounds__(512) void off_scan_kernel(const int* __restrict__ blockHist,
                                                       int NB1, int NRP,
                                                       int* __restrict__ off,
                                                       int* __restrict__ total) {
    const int r = (blockIdx.x * 512 + threadIdx.x) >> 6;
    const int lane = threadIdx.x & 63;
    if (r >= NRP) return;
    int carry = 0;
    const int chunks = (NB1 + 63) / 64;
    for (int c = 0; c < chunks; ++c) {
        const int b = c * 64 + lane;
        const int v = (b < NB1) ? blockHist[b * NRP + r] : 0;
        int x = v;
#pragma unroll
        for (int d = 1; d < 64; d <<= 1) {
            int y = __shfl_up(x, d, 64);
            if (lane >= d) x += y;
        }
        if (b < NB1) off[b * NRP + r] = carry + (x - v);
        carry += __shfl(x, 63, 64);
    }
    if (lane == 0) total[r] = carry;
}

// ---------------- pass 2b: exclusive scan of totals -> rangeBase ------------
__global__ __launch_bounds__(1024) void range_scan_kernel(const int* __restrict__ total,
                                                          int NRP, int* __restrict__ rangeBase) {
    __shared__ int s[1024];
    const int t = threadIdx.x;
    const int v = (t < NRP) ? total[t] : 0;
    s[t] = v;
    __syncthreads();
    for (int off = 1; off < 1024; off <<= 1) {
        int add = (t >= off) ? s[t - off] : 0;
        __syncthreads();
        s[t] += add;
        __syncthreads();
    }
    if (t < NRP) rangeBase[t] = s[t] - v;
}

// ---------------- pass 1b: LDS-ranked scatter into range buckets ------------
__global__ __launch_bounds__(BS) void bucket_scatter_kernel(
    const int* __restrict__ ei, int E, int NRP, const int* __restrict__ off,
    const int* __restrict__ rangeBase, int2* __restrict__ sedgeB) {
    __shared__ int2 stage[K1_EDGES];          // 32 KB
    __shared__ unsigned short inv[K1_EDGES];  // 8 KB
    __shared__ int hist[1024], start[1024], cursor[1024];
    __shared__ int ts[BS];
    const int tid = threadIdx.x;
    for (int r = tid; r < 1024; r += BS) hist[r] = 0;
    __syncthreads();
    const int base = blockIdx.x * K1_EDGES;
    const int M = min(K1_EDGES, E - base);
    for (int i = tid; i < M; i += BS) {
        const int2 p = make_int2(ei[base + i], ei[E + base + i]);
        stage[i] = p;
        atomicAdd(&hist[p.y >> 7], 1);
    }
    __syncthreads();
    {
        const int i0 = tid * 4;
        const int l0 = hist[i0], l1 = hist[i0 + 1], l2 = hist[i0 + 2], l3 = hist[i0 + 3];
        const int tsum = l0 + l1 + l2 + l3;
        ts[tid] = tsum;
        __syncthreads();
        for (int off2 = 1; off2 < BS; off2 <<= 1) {
            int add = (tid >= off2) ? ts[tid - off2] : 0;
            __syncthreads();
            ts[tid] += add;
            __syncthreads();
        }
        const int texcl = ts[tid] - tsum;
        start[i0] = texcl;
        start[i0 + 1] = texcl + l0;
        start[i0 + 2] = texcl + l0 + l1;
        start[i0 + 3] = texcl + l0 + l1 + l2;
        cursor[i0] = start[i0];
        cursor[i0 + 1] = start[i0 + 1];
        cursor[i0 + 2] = start[i0 + 2];
        cursor[i0 + 3] = start[i0 + 3];
    }
    __syncthreads();
    for (int i = tid; i < M; i += BS) {
        const int pos = atomicAdd(&cursor[stage[i].y >> 7], 1);
        inv[pos] = (unsigned short)i;
    }
    __syncthreads();
    const int* offb = off + blockIdx.x * NRP;
    for (int j = tid; j < M; j += BS) {
        const int2 p = stage[inv[j]];
        const int r = p.y >> 7;
        sedgeB[rangeBase[r] + offb[r] + (j - start[r])] = p;  // contiguous runs
    }
}

// Layer 2 prep: reads layer-1 agg as plain float (already relu'd).
__global__ __launch_bounds__(BS) void prep2_kernel(const float* __restrict__ pos,
                                                   const float* __restrict__ aggA,
                                                   const float* __restrict__ Wa,
                                                   const float* __restrict__ ba,
                                                   unsigned* __restrict__ Ubf,
                                                   float* __restrict__ V, int N) {
    int n = blockIdx.x * BS + threadIdx.x;
    if (n >= N) return;
    float h[32];
    const float4* hp = reinterpret_cast<const float4*>(aggA + (size_t)n * 32);
#pragma unroll
    for (int q = 0; q < 8; ++q) {
        float4 t = hp[q];
        h[4 * q + 0] = t.x;
        h[4 * q + 1] = t.y;
        h[4 * q + 2] = t.z;
        h[4 * q + 3] = t.w;
    }
    const float p[3] = {pos[3 * n], pos[3 * n + 1], pos[3 * n + 2]};
    v2f u[16], v[16];
#pragma unroll
    for (int g = 0; g < 16; ++g) {
        u[g] = *reinterpret_cast<const v2f*>(&ba[g * 2]);
        v2f z = {0.0f, 0.0f};
        v[g] = z;
    }
#pragma unroll
    for (int i = 0; i < 32; ++i) {
        const v2f f = {h[i], h[i]};
#pragma unroll
        for (int g = 0; g < 16; ++g) {
            const v2f w = *reinterpret_cast<const v2f*>(&Wa[i * 32 + g * 2]);
            u[g] = __builtin_elementwise_fma(f, w, u[g]);
        }
    }
#pragma unroll
    for (int i = 0; i < 3; ++i) {
        const v2f f = {p[i], p[i]};
#pragma unroll
        for (int g = 0; g < 16; ++g) {
            const v2f w = *reinterpret_cast<const v2f*>(&Wa[(32 + i) * 32 + g * 2]);
            u[g] = __builtin_elementwise_fma(f, w, u[g]);
            v[g] = __builtin_elementwise_fma(f, w, v[g]);
        }
    }
    uint4* Up = reinterpret_cast<uint4*>(Ubf + (size_t)n * 16);
    float4* Vp = reinterpret_cast<float4*>(V + (size_t)n * 32);
#pragma unroll
    for (int q = 0; q < 4; ++q) {
        uint4 o;
        o.x = cvt2(u[4 * q + 0].x, u[4 * q + 0].y);
        o.y = cvt2(u[4 * q + 1].x, u[4 * q + 1].y);
        o.z = cvt2(u[4 * q + 2].x, u[4 * q + 2].y);
        o.w = cvt2(u[4 * q + 3].x, u[4 * q + 3].y);
        Up[q] = o;
    }
#pragma unroll
    for (int q = 0; q < 8; ++q)
        Vp[q] = make_float4(v[2 * q].x, v[2 * q].y, v[2 * q + 1].x, v[2 * q + 1].y);
}

// ---------------- range-bucket edge kernel (8 waves / 512-edge chunks) ------
// One block per range of 128 dsts. Wave w handles chunk edges [64w, 64w+64);
// waves skip chunks past M. sedgeB descriptors prefetched one chunk ahead.
// V (128 contiguous rows, 16 KB) staged in LDS with stride-9 float4 padding.
// LDS atomicMax into aggL; exclusive relu'd-float writeout.
__global__ __launch_bounds__(EBS, 6) void edge_range_kernel(
    const unsigned* __restrict__ Ubf, const float4* __restrict__ V,
    const int2* __restrict__ sedgeB, const int* __restrict__ rangeBase,
    const int* __restrict__ total, const unsigned* __restrict__ WbtG,
    const float* __restrict__ bb, float* __restrict__ out, int N) {
    __shared__ unsigned aggL[4096];              // [128 dst][32 ch], 16 KB
    __shared__ __align__(16) float4 vlds[1152];  // [128 rows][9 f4] (8 used), 18 KB

    const int tid = threadIdx.x;
    const int r = blockIdx.x;
    const int base = rangeBase[r];
    const int M = total[r];
    const int last = M - 1;

    const int l = tid & 63;
    const int w = tid >> 6;  // 0..7: wave w owns chunk edges [64w, 64w+64)
    const int half = l >> 5;
    const int ln = l & 31;

#pragma unroll
    for (int i = 0; i < 8; ++i) aggL[tid + i * EBS] = ORD_NEG_INF;

    // stage V rows [128r, 128r+128): coalesced, padded stride 9
    {
        const float4* Vg = V + ((size_t)r << 10);          // row 128r, 8 f4/row
        const int vmax = min(1024, (N - (r << 7)) * 8);    // clamp at N
        for (int j = tid; j < vmax; j += EBS) vlds[(j >> 3) * 9 + (j & 7)] = Vg[j];
    }

    // B fragments: precomputed per-lane packed bf16 (L1-hot, 2 loads)
    const uint4 bu0 = *reinterpret_cast<const uint4*>(WbtG + l * 8);
    const uint4 bu1 = *reinterpret_cast<const uint4*>(WbtG + l * 8 + 4);
    const float bbn = bb[ln];
    __syncthreads();  // aggL init + V stage visible

    const int nch = (M + EBS - 1) >> 9;
    int2 edA, edB;
    if (64 * w < M) {  // prologue: chunk-0 edge descriptors
        const int j0 = min(64 * w + ln, last);
        const int j1 = min(j0 + 32, last);
        edA = sedgeB[base + j0];
        edB = sedgeB[base + j1];
    }
    for (int c = 0; c < nch; ++c) {
        // prefetch next chunk's descriptors (wave-uniform participation)
        int2 nA, nB;
        const int ncb = (c + 1) << 9;
        const bool nextAct = (c + 1 < nch) && (ncb + 64 * w < M);
        if (nextAct) {
            const int j0 = min(ncb + 64 * w + ln, last);
            const int j1 = min(j0 + 32, last);
            nA = sedgeB[base + j0];
            nB = sedgeB[base + j1];
        }
        if ((c << 9) + 64 * w < M) {  // this wave active this chunk
            uint4 au00, au01, au10, au11;
            {
                const uint4* Up = reinterpret_cast<const uint4*>(Ubf + (size_t)edA.x * 16);
                const float4* Vr = &vlds[(edA.y & 127) * 9];
                au00 = mk_frag(Up[half], Vr[2 * half], Vr[2 * half + 1]);
                au01 = mk_frag(Up[2 + half], Vr[4 + 2 * half], Vr[5 + 2 * half]);
            }
            {
                const uint4* Up = reinterpret_cast<const uint4*>(Ubf + (size_t)edB.x * 16);
                const float4* Vr = &vlds[(edB.y & 127) * 9];
                au10 = mk_frag(Up[half], Vr[2 * half], Vr[2 * half + 1]);
                au11 = mk_frag(Up[2 + half], Vr[4 + 2 * half], Vr[5 + 2 * half]);
            }

            f32x16 c0, c1;
#pragma unroll
            for (int i = 0; i < 16; ++i) {
                c0[i] = bbn;
                c1[i] = bbn;
            }
            c0 = __builtin_amdgcn_mfma_f32_32x32x16_bf16(
                __builtin_bit_cast(bf16x8, au00), __builtin_bit_cast(bf16x8, bu0), c0, 0, 0, 0);
            c0 = __builtin_amdgcn_mfma_f32_32x32x16_bf16(
                __builtin_bit_cast(bf16x8, au01), __builtin_bit_cast(bf16x8, bu1), c0, 0, 0, 0);
            c1 = __builtin_amdgcn_mfma_f32_32x32x16_bf16(
                __builtin_bit_cast(bf16x8, au10), __builtin_bit_cast(bf16x8, bu0), c1, 0, 0, 0);
            c1 = __builtin_amdgcn_mfma_f32_32x32x16_bf16(
                __builtin_bit_cast(bf16x8, au11), __builtin_bit_cast(bf16x8, bu1), c1, 0, 0, 0);

            // scatter-max: C row rr <-> edge offset eo = (rr&3)+8(rr>>2)+4h,
            // edge eo of this wave (c0) / eo+32 (c1). dst via __shfl.
            // aggL addr (dl<<5)|ln: lanes of a half hit distinct banks.
#pragma unroll
            for (int rr = 0; rr < 16; ++rr) {
                const int eo = (rr & 3) + 8 * (rr >> 2) + 4 * half;
                const int d0 = __shfl(edA.y, eo, 64);
                const int d1 = __shfl(edB.y, eo, 64);
                atomicMax(&aggL[((d0 & 127) << 5) | ln], ordenc(c0[rr]));
                atomicMax(&aggL[((d1 & 127) << 5) | ln], ordenc(c1[rr]));
            }
        }
        edA = nA;  // garbage if !nextAct, but then unused next iter
        edB = nB;
    }
    __syncthreads();

    // exclusive writeout: 4096 values, 8 per thread, decode + relu -> float
    const int idx = tid * 8;
    const int node = (r << 7) + (idx >> 5);
    if (node < N) {
        float4 o0, o1;
        o0.x = fmaxf(orddec(aggL[idx + 0]), 0.0f);
        o0.y = fmaxf(orddec(aggL[idx + 1]), 0.0f);
        o0.z = fmaxf(orddec(aggL[idx + 2]), 0.0f);
        o0.w = fmaxf(orddec(aggL[idx + 3]), 0.0f);
        o1.x = fmaxf(orddec(aggL[idx + 4]), 0.0f);
        o1.y = fmaxf(orddec(aggL[idx + 5]), 0.0f);
        o1.z = fmaxf(orddec(aggL[idx + 6]), 0.0f);
        o1.w = fmaxf(orddec(aggL[idx + 7]), 0.0f);
        float4* op = reinterpret_cast<float4*>(out + (size_t)node * 32 + (idx & 31));
        op[0] = o0;
        op[1] = o1;
    }
}

extern "C" void kernel_launch(void* const* d_in, const int* in_sizes, int n_in,
                              void* d_out, int out_size, void* d_ws, size_t ws_size,
                              hipStream_t stream) {
    const float* pos = (const float*)d_in[0];
    const int* ei = (const int*)d_in[1];
    const float* W1 = (const float*)d_in[3];
    const float* b1 = (const float*)d_in[4];
    const float* W2 = (const float*)d_in[5];
    const float* b2 = (const float*)d_in[6];
    const float* W3 = (const float*)d_in[7];
    const float* b3 = (const float*)d_in[8];
    const float* W4 = (const float*)d_in[9];
    const float* b4 = (const float*)d_in[10];

    const int E = in_sizes[1] / 2;
    const int N = in_sizes[0] / 3;
    const int n32 = N * 32;
    const int NPAD = ((N + BS - 1) / BS) * BS;
    const int NR = (N + 127) / 128;         // ranges of 128 dsts
    const int NRP = ((NR + 15) / 16) * 16;  // padded (<= 1024)
    const int NB1 = (E + K1_EDGES - 1) / K1_EDGES;
    const int BH = NB1 * NRP;

    int* blockHist = (int*)d_ws;              // BH
    int* off = blockHist + BH;                // BH
    int* total = off + BH;                    // NRP
    int* rangeBase = total + NRP;             // NRP
    int2* sedgeB = (int2*)(rangeBase + NRP);  // E (range-grouped edges)
    float* aggA = (float*)(sedgeB + E);       // n32 (layer-1 h, relu'd float)
    unsigned* Ubf = (unsigned*)(aggA + n32);  // NPAD*16 (bf16-packed U)
    float* Vbuf = (float*)(Ubf + (size_t)NPAD * 16);  // n32
    unsigned* WbtG = (unsigned*)(Vbuf + n32);         // 1024 dw (2 layers x 512)

    const int NBn = (N + BS - 1) / BS;

    // fused: hist | prep1 | Wbt pack (mutually independent)
    setup_kernel<<<NB1 + NBn + 1, BS, 0, stream>>>(ei, E, NRP, blockHist, pos, W1, b1, Ubf,
                                                   Vbuf, N, NB1, NBn, W2, W4, WbtG);
    off_scan_kernel<<<(NRP * 64 + 511) / 512, 512, 0, stream>>>(blockHist, NB1, NRP, off,
                                                                total);
    range_scan_kernel<<<1, 1024, 0, stream>>>(total, NRP, rangeBase);
    bucket_scatter_kernel<<<NB1, BS, 0, stream>>>(ei, E, NRP, off, rangeBase, sedgeB);

    // --- layer 1 ---
    edge_range_kernel<<<NR, EBS, 0, stream>>>(Ubf, (const float4*)Vbuf, sedgeB, rangeBase,
                                              total, WbtG, b2, aggA, N);
    // --- layer 2 ---
    prep2_kernel<<<NBn, BS, 0, stream>>>(pos, aggA, W3, b3, Ubf, Vbuf, N);
    edge_range_kernel<<<NR, EBS, 0, stream>>>(Ubf, (const float4*)Vbuf, sedgeB, rangeBase,
                                              total, WbtG + 512, b4, (float*)d_out, N);
}

// Round 6
// 212.660 us; speedup vs baseline: 1.9420x; 1.0134x over previous
//
#include <hip/hip_runtime.h>
#include <hip/hip_bf16.h>
#include <stdint.h>

// PointNet EdgeConv, 2 layers. Round 20 (resubmit — infra failure, not kernel).
// R14: cvt_pk_bf16 + bf16 m-matrix + bias-in-C.                233 us
// R15: fused setup; 512-edge edge_seg blocks.                  230 us
// R17: range-bucket edge kernel (4 kernels deleted).           252 us
// R18: launch_bounds(1024,8) -> VGPR spill disaster.           413 us
// R19: spill fix + V-in-LDS + tail skip + desc prefetch.       215 us <- best
// R20: u32-packed edge descriptors (src | dstLocal<<20).
//      * edge_range loads descriptors LINEARLY (lane l -> edge cb+64w+l,
//        one coalesced 4B load covers both halves; A/B roles + rr-loop dsts
//        all via __shfl). Descriptor HBM: 64 MB -> 19 MB total.
//      * bucket_scatter stages u32 + u16 range id: LDS 53->45 KB, store
//        traffic halved (6.4 MB).
//      Numerics identical.

#define BS 256
#define EBS 512        // edge kernel block size / chunk (512 edges)
#define K1_EDGES 4096  // edges staged per block in scatter pass

typedef float v2f __attribute__((ext_vector_type(2)));
typedef __attribute__((ext_vector_type(8))) short bf16x8;
typedef __attribute__((ext_vector_type(16))) float f32x16;
typedef __bf16 bf16v2 __attribute__((ext_vector_type(2)));

__device__ __forceinline__ unsigned ordenc(float f) {
    unsigned u = __float_as_uint(f);
    return (u & 0x80000000u) ? ~u : (u | 0x80000000u);
}
__device__ __forceinline__ float orddec(unsigned o) {
    unsigned u = (o & 0x80000000u) ? (o ^ 0x80000000u) : ~o;
    return __uint_as_float(u);
}
#define ORD_NEG_INF 0x007FFFFFu  // ordenc(-inf)
#define SRC_MASK 0xFFFFFu        // 20-bit src field (N < 1M)

// two f32 -> packed bf16 pair (RNE) via v_cvt_pk_bf16_f32; x -> low half
__device__ __forceinline__ unsigned cvt2(float x, float y) {
    v2f v = {x, y};
    bf16v2 b = __builtin_convertvector(v, bf16v2);
    return __builtin_bit_cast(unsigned, b);
}
__device__ __forceinline__ float bflo(unsigned u) { return __uint_as_float(u << 16); }
__device__ __forceinline__ float bfhi(unsigned u) { return __uint_as_float(u & 0xFFFF0000u); }

// build 8 channels of h = relu(bf16(U) - V) as 4 packed bf16 pairs
__device__ __forceinline__ uint4 mk_frag(uint4 ua, float4 v0, float4 v1) {
    uint4 o;
    o.x = cvt2(fmaxf(bflo(ua.x) - v0.x, 0.0f), fmaxf(bfhi(ua.x) - v0.y, 0.0f));
    o.y = cvt2(fmaxf(bflo(ua.y) - v0.z, 0.0f), fmaxf(bfhi(ua.y) - v0.w, 0.0f));
    o.z = cvt2(fmaxf(bflo(ua.z) - v1.x, 0.0f), fmaxf(bfhi(ua.z) - v1.y, 0.0f));
    o.w = cvt2(fmaxf(bflo(ua.w) - v1.z, 0.0f), fmaxf(bfhi(ua.w) - v1.w, 0.0f));
    return o;
}

// ---------------- fused setup: range-hist | prep1 | Wbt pack ----------------
__global__ __launch_bounds__(BS) void setup_kernel(
    const int* __restrict__ ei, int E, int NRP, int* __restrict__ blockHist,
    const float* __restrict__ pos, const float* __restrict__ Wa, const float* __restrict__ ba,
    unsigned* __restrict__ Ubf, float* __restrict__ V, int N, int NB1, int NBn,
    const float* __restrict__ Wb2, const float* __restrict__ Wb4,
    unsigned* __restrict__ WbtG) {
    __shared__ int hist[1024];
    const int tid = threadIdx.x;
    const int b = blockIdx.x;
    if (b < NB1) {
        for (int r = tid; r < 1024; r += BS) hist[r] = 0;
        __syncthreads();
        const int base = b * K1_EDGES;
        const int M = min(K1_EDGES, E - base);
        for (int i = tid; i < M; i += BS) atomicAdd(&hist[ei[E + base + i] >> 7], 1);
        __syncthreads();
        for (int r = tid; r < NRP; r += BS) blockHist[b * NRP + r] = hist[r];
    } else if (b < NB1 + NBn) {
        const int n = (b - NB1) * BS + tid;
        if (n >= N) return;
        const float p[3] = {pos[3 * n], pos[3 * n + 1], pos[3 * n + 2]};
        v2f u[16], v[16];
#pragma unroll
        for (int g = 0; g < 16; ++g) {
            u[g] = *reinterpret_cast<const v2f*>(&ba[g * 2]);
            v2f z = {0.0f, 0.0f};
            v[g] = z;
        }
#pragma unroll
        for (int i = 0; i < 3; ++i) {
            const v2f f = {p[i], p[i]};
#pragma unroll
            for (int g = 0; g < 16; ++g) {
                const v2f wA = *reinterpret_cast<const v2f*>(&Wa[i * 32 + g * 2]);
                const v2f wB = *reinterpret_cast<const v2f*>(&Wa[(i + 3) * 32 + g * 2]);
                u[g] = __builtin_elementwise_fma(f, wA + wB, u[g]);
                v[g] = __builtin_elementwise_fma(f, wB, v[g]);
            }
        }
        uint4* Up = reinterpret_cast<uint4*>(Ubf + (size_t)n * 16);
        float4* Vp = reinterpret_cast<float4*>(V + (size_t)n * 32);
#pragma unroll
        for (int q = 0; q < 4; ++q) {
            uint4 o;
            o.x = cvt2(u[4 * q + 0].x, u[4 * q + 0].y);
            o.y = cvt2(u[4 * q + 1].x, u[4 * q + 1].y);
            o.z = cvt2(u[4 * q + 2].x, u[4 * q + 2].y);
            o.w = cvt2(u[4 * q + 3].x, u[4 * q + 3].y);
            Up[q] = o;
        }
#pragma unroll
        for (int q = 0; q < 8; ++q)
            Vp[q] = make_float4(v[2 * q].x, v[2 * q].y, v[2 * q + 1].x, v[2 * q + 1].y);
    } else {
        // pack per-lane B fragments (bf16 pairs) for both layers: 2 x 512 dw
        if (tid < 128) {
            const int layer = tid >> 6;
            const int t = tid & 63;
            const int lnp = t & 31;
            const int hp = t >> 5;
            const float* Wb = layer ? Wb4 : Wb2;
            unsigned* dst = WbtG + layer * 512 + t * 8;
#pragma unroll
            for (int q = 0; q < 4; ++q) {
                const int p = 4 * hp + q;
                dst[q] = cvt2(Wb[(2 * p) * 32 + lnp], Wb[(2 * p + 1) * 32 + lnp]);
                dst[4 + q] = cvt2(Wb[(2 * p + 16) * 32 + lnp], Wb[(2 * p + 17) * 32 + lnp]);
            }
        }
    }
}

// ---------------- pass 2a: per-(block,range) LOCAL prefixes + range totals --
__global__ __launch_bounds__(512) void off_scan_kernel(const int* __restrict__ blockHist,
                                                       int NB1, int NRP,
                                                       int* __restrict__ off,
                                                       int* __restrict__ total) {
    const int r = (blockIdx.x * 512 + threadIdx.x) >> 6;
    const int lane = threadIdx.x & 63;
    if (r >= NRP) return;
    int carry = 0;
    const int chunks = (NB1 + 63) / 64;
    for (int c = 0; c < chunks; ++c) {
        const int b = c * 64 + lane;
        const int v = (b < NB1) ? blockHist[b * NRP + r] : 0;
        int x = v;
#pragma unroll
        for (int d = 1; d < 64; d <<= 1) {
            int y = __shfl_up(x, d, 64);
            if (lane >= d) x += y;
        }
        if (b < NB1) off[b * NRP + r] = carry + (x - v);
        carry += __shfl(x, 63, 64);
    }
    if (lane == 0) total[r] = carry;
}

// ---------------- pass 2b: exclusive scan of totals -> rangeBase ------------
__global__ __launch_bounds__(1024) void range_scan_kernel(const int* __restrict__ total,
                                                          int NRP, int* __restrict__ rangeBase) {
    __shared__ int s[1024];
    const int t = threadIdx.x;
    const int v = (t < NRP) ? total[t] : 0;
    s[t] = v;
    __syncthreads();
    for (int off = 1; off < 1024; off <<= 1) {
        int add = (t >= off) ? s[t - off] : 0;
        __syncthreads();
        s[t] += add;
        __syncthreads();
    }
    if (t < NRP) rangeBase[t] = s[t] - v;
}

// ---------------- pass 1b: LDS-ranked scatter into range buckets ------------
// Stages u32-packed edges (src | dstLocal<<20) + u16 range ids.
__global__ __launch_bounds__(BS) void bucket_scatter_kernel(
    const int* __restrict__ ei, int E, int NRP, const int* __restrict__ off,
    const int* __restrict__ rangeBase, unsigned* __restrict__ sedgeB) {
    __shared__ unsigned stage[K1_EDGES];      // 16 KB
    __shared__ unsigned short rng[K1_EDGES];  // 8 KB
    __shared__ unsigned short inv[K1_EDGES];  // 8 KB
    __shared__ int hist[1024], start[1024], cursor[1024];
    __shared__ int ts[BS];
    const int tid = threadIdx.x;
    for (int r = tid; r < 1024; r += BS) hist[r] = 0;
    __syncthreads();
    const int base = blockIdx.x * K1_EDGES;
    const int M = min(K1_EDGES, E - base);
    for (int i = tid; i < M; i += BS) {
        const int src = ei[base + i];
        const int dst = ei[E + base + i];
        const int r = dst >> 7;
        stage[i] = (unsigned)src | ((unsigned)(dst & 127) << 20);
        rng[i] = (unsigned short)r;
        atomicAdd(&hist[r], 1);
    }
    __syncthreads();
    {
        const int i0 = tid * 4;
        const int l0 = hist[i0], l1 = hist[i0 + 1], l2 = hist[i0 + 2], l3 = hist[i0 + 3];
        const int tsum = l0 + l1 + l2 + l3;
        ts[tid] = tsum;
        __syncthreads();
        for (int off2 = 1; off2 < BS; off2 <<= 1) {
            int add = (tid >= off2) ? ts[tid - off2] : 0;
            __syncthreads();
            ts[tid] += add;
            __syncthreads();
        }
        const int texcl = ts[tid] - tsum;
        start[i0] = texcl;
        start[i0 + 1] = texcl + l0;
        start[i0 + 2] = texcl + l0 + l1;
        start[i0 + 3] = texcl + l0 + l1 + l2;
        cursor[i0] = start[i0];
        cursor[i0 + 1] = start[i0 + 1];
        cursor[i0 + 2] = start[i0 + 2];
        cursor[i0 + 3] = start[i0 + 3];
    }
    __syncthreads();
    for (int i = tid; i < M; i += BS) {
        const int pos = atomicAdd(&cursor[rng[i]], 1);
        inv[pos] = (unsigned short)i;
    }
    __syncthreads();
    const int* offb = off + blockIdx.x * NRP;
    for (int j = tid; j < M; j += BS) {
        const int i = inv[j];
        const int r = rng[i];
        sedgeB[rangeBase[r] + offb[r] + (j - start[r])] = stage[i];  // contiguous runs
    }
}

// Layer 2 prep: reads layer-1 agg as plain float (already relu'd).
__global__ __launch_bounds__(BS) void prep2_kernel(const float* __restrict__ pos,
                                                   const float* __restrict__ aggA,
                                                   const float* __restrict__ Wa,
                                                   const float* __restrict__ ba,
                                                   unsigned* __restrict__ Ubf,
                                                   float* __restrict__ V, int N) {
    int n = blockIdx.x * BS + threadIdx.x;
    if (n >= N) return;
    float h[32];
    const float4* hp = reinterpret_cast<const float4*>(aggA + (size_t)n * 32);
#pragma unroll
    for (int q = 0; q < 8; ++q) {
        float4 t = hp[q];
        h[4 * q + 0] = t.x;
        h[4 * q + 1] = t.y;
        h[4 * q + 2] = t.z;
        h[4 * q + 3] = t.w;
    }
    const float p[3] = {pos[3 * n], pos[3 * n + 1], pos[3 * n + 2]};
    v2f u[16], v[16];
#pragma unroll
    for (int g = 0; g < 16; ++g) {
        u[g] = *reinterpret_cast<const v2f*>(&ba[g * 2]);
        v2f z = {0.0f, 0.0f};
        v[g] = z;
    }
#pragma unroll
    for (int i = 0; i < 32; ++i) {
        const v2f f = {h[i], h[i]};
#pragma unroll
        for (int g = 0; g < 16; ++g) {
            const v2f w = *reinterpret_cast<const v2f*>(&Wa[i * 32 + g * 2]);
            u[g] = __builtin_elementwise_fma(f, w, u[g]);
        }
    }
#pragma unroll
    for (int i = 0; i < 3; ++i) {
        const v2f f = {p[i], p[i]};
#pragma unroll
        for (int g = 0; g < 16; ++g) {
            const v2f w = *reinterpret_cast<const v2f*>(&Wa[(32 + i) * 32 + g * 2]);
            u[g] = __builtin_elementwise_fma(f, w, u[g]);
            v[g] = __builtin_elementwise_fma(f, w, v[g]);
        }
    }
    uint4* Up = reinterpret_cast<uint4*>(Ubf + (size_t)n * 16);
    float4* Vp = reinterpret_cast<float4*>(V + (size_t)n * 32);
#pragma unroll
    for (int q = 0; q < 4; ++q) {
        uint4 o;
        o.x = cvt2(u[4 * q + 0].x, u[4 * q + 0].y);
        o.y = cvt2(u[4 * q + 1].x, u[4 * q + 1].y);
        o.z = cvt2(u[4 * q + 2].x, u[4 * q + 2].y);
        o.w = cvt2(u[4 * q + 3].x, u[4 * q + 3].y);
        Up[q] = o;
    }
#pragma unroll
    for (int q = 0; q < 8; ++q)
        Vp[q] = make_float4(v[2 * q].x, v[2 * q].y, v[2 * q + 1].x, v[2 * q + 1].y);
}

// ---------------- range-bucket edge kernel (8 waves / 512-edge chunks) ------
// One block per range of 128 dsts. Lane l loads the u32 descriptor of edge
// cb+64w+l (coalesced, once); A/B fragment roles and rr-loop dsts via __shfl.
// V staged in LDS (stride-9 f4 pad). LDS atomicMax into aggL; exclusive
// relu'd-float writeout.
__global__ __launch_bounds__(EBS, 6) void edge_range_kernel(
    const unsigned* __restrict__ Ubf, const float4* __restrict__ V,
    const unsigned* __restrict__ sedgeB, const int* __restrict__ rangeBase,
    const int* __restrict__ total, const unsigned* __restrict__ WbtG,
    const float* __restrict__ bb, float* __restrict__ out, int N) {
    __shared__ unsigned aggL[4096];              // [128 dst][32 ch], 16 KB
    __shared__ __align__(16) float4 vlds[1152];  // [128 rows][9 f4] (8 used), 18 KB

    const int tid = threadIdx.x;
    const int r = blockIdx.x;
    const int base = rangeBase[r];
    const int M = total[r];
    const int last = M - 1;

    const int l = tid & 63;
    const int w = tid >> 6;  // 0..7: wave w owns chunk edges [64w, 64w+64)
    const int half = l >> 5;
    const int ln = l & 31;

#pragma unroll
    for (int i = 0; i < 8; ++i) aggL[tid + i * EBS] = ORD_NEG_INF;

    // stage V rows [128r, 128r+128): coalesced, padded stride 9
    {
        const float4* Vg = V + ((size_t)r << 10);        // row 128r, 8 f4/row
        const int vmax = min(1024, (N - (r << 7)) * 8);  // clamp at N
        for (int j = tid; j < vmax; j += EBS) vlds[(j >> 3) * 9 + (j & 7)] = Vg[j];
    }

    // B fragments: precomputed per-lane packed bf16 (L1-hot, 2 loads)
    const uint4 bu0 = *reinterpret_cast<const uint4*>(WbtG + l * 8);
    const uint4 bu1 = *reinterpret_cast<const uint4*>(WbtG + l * 8 + 4);
    const float bbn = bb[ln];
    __syncthreads();  // aggL init + V stage visible

    const int nch = (M + EBS - 1) >> 9;
    unsigned pk = 0;
    if (64 * w < M) pk = sedgeB[base + min(64 * w + l, last)];  // chunk-0 descs
    for (int c = 0; c < nch; ++c) {
        // prefetch next chunk's descriptors (wave-uniform participation)
        unsigned npk = 0;
        const int ncb = (c + 1) << 9;
        const bool nextAct = (c + 1 < nch) && (ncb + 64 * w < M);
        if (nextAct) npk = sedgeB[base + min(ncb + 64 * w + l, last)];
        if ((c << 9) + 64 * w < M) {  // this wave active this chunk
            const unsigned pkA = __shfl(pk, ln, 64);       // edge cb+64w+ln
            const unsigned pkB = __shfl(pk, 32 + ln, 64);  // edge cb+64w+32+ln
            uint4 au00, au01, au10, au11;
            {
                const uint4* Up = reinterpret_cast<const uint4*>(Ubf + (size_t)(pkA & SRC_MASK) * 16);
                const float4* Vr = &vlds[(pkA >> 20) * 9];
                au00 = mk_frag(Up[half], Vr[2 * half], Vr[2 * half + 1]);
                au01 = mk_frag(Up[2 + half], Vr[4 + 2 * half], Vr[5 + 2 * half]);
            }
            {
                const uint4* Up = reinterpret_cast<const uint4*>(Ubf + (size_t)(pkB & SRC_MASK) * 16);
                const float4* Vr = &vlds[(pkB >> 20) * 9];
                au10 = mk_frag(Up[half], Vr[2 * half], Vr[2 * half + 1]);
                au11 = mk_frag(Up[2 + half], Vr[4 + 2 * half], Vr[5 + 2 * half]);
            }

            f32x16 c0, c1;
#pragma unroll
            for (int i = 0; i < 16; ++i) {
                c0[i] = bbn;
                c1[i] = bbn;
            }
            c0 = __builtin_amdgcn_mfma_f32_32x32x16_bf16(
                __builtin_bit_cast(bf16x8, au00), __builtin_bit_cast(bf16x8, bu0), c0, 0, 0, 0);
            c0 = __builtin_amdgcn_mfma_f32_32x32x16_bf16(
                __builtin_bit_cast(bf16x8, au01), __builtin_bit_cast(bf16x8, bu1), c0, 0, 0, 0);
            c1 = __builtin_amdgcn_mfma_f32_32x32x16_bf16(
                __builtin_bit_cast(bf16x8, au10), __builtin_bit_cast(bf16x8, bu0), c1, 0, 0, 0);
            c1 = __builtin_amdgcn_mfma_f32_32x32x16_bf16(
                __builtin_bit_cast(bf16x8, au11), __builtin_bit_cast(bf16x8, bu1), c1, 0, 0, 0);

            // scatter-max: C row rr <-> edge offset eo = (rr&3)+8(rr>>2)+4h;
            // edge cb+64w+eo held by lane eo (c0) / lane 32+eo (c1).
            // aggL addr (dl<<5)|ln: lanes of a half hit distinct banks.
#pragma unroll
            for (int rr = 0; rr < 16; ++rr) {
                const int eo = (rr & 3) + 8 * (rr >> 2) + 4 * half;
                const int d0 = __shfl(pk, eo, 64) >> 20;
                const int d1 = __shfl(pk, 32 + eo, 64) >> 20;
                atomicMax(&aggL[(d0 << 5) | ln], ordenc(c0[rr]));
                atomicMax(&aggL[(d1 << 5) | ln], ordenc(c1[rr]));
            }
        }
        pk = npk;  // garbage if !nextAct, but then unused next iter
    }
    __syncthreads();

    // exclusive writeout: 4096 values, 8 per thread, decode + relu -> float
    const int idx = tid * 8;
    const int node = (r << 7) + (idx >> 5);
    if (node < N) {
        float4 o0, o1;
        o0.x = fmaxf(orddec(aggL[idx + 0]), 0.0f);
        o0.y = fmaxf(orddec(aggL[idx + 1]), 0.0f);
        o0.z = fmaxf(orddec(aggL[idx + 2]), 0.0f);
        o0.w = fmaxf(orddec(aggL[idx + 3]), 0.0f);
        o1.x = fmaxf(orddec(aggL[idx + 4]), 0.0f);
        o1.y = fmaxf(orddec(aggL[idx + 5]), 0.0f);
        o1.z = fmaxf(orddec(aggL[idx + 6]), 0.0f);
        o1.w = fmaxf(orddec(aggL[idx + 7]), 0.0f);
        float4* op = reinterpret_cast<float4*>(out + (size_t)node * 32 + (idx & 31));
        op[0] = o0;
        op[1] = o1;
    }
}

extern "C" void kernel_launch(void* const* d_in, const int* in_sizes, int n_in,
                              void* d_out, int out_size, void* d_ws, size_t ws_size,
                              hipStream_t stream) {
    const float* pos = (const float*)d_in[0];
    const int* ei = (const int*)d_in[1];
    const float* W1 = (const float*)d_in[3];
    const float* b1 = (const float*)d_in[4];
    const float* W2 = (const float*)d_in[5];
    const float* b2 = (const float*)d_in[6];
    const float* W3 = (const float*)d_in[7];
    const float* b3 = (const float*)d_in[8];
    const float* W4 = (const float*)d_in[9];
    const float* b4 = (const float*)d_in[10];

    const int E = in_sizes[1] / 2;
    const int N = in_sizes[0] / 3;
    const int n32 = N * 32;
    const int NPAD = ((N + BS - 1) / BS) * BS;
    const int NR = (N + 127) / 128;         // ranges of 128 dsts
    const int NRP = ((NR + 15) / 16) * 16;  // padded (<= 1024)
    const int NB1 = (E + K1_EDGES - 1) / K1_EDGES;
    const int BH = NB1 * NRP;

    int* blockHist = (int*)d_ws;                  // BH
    int* off = blockHist + BH;                    // BH
    int* total = off + BH;                        // NRP
    int* rangeBase = total + NRP;                 // NRP
    unsigned* sedgeB = (unsigned*)(rangeBase + NRP);  // E (u32-packed edges)
    float* aggA = (float*)(sedgeB + E);           // n32 (layer-1 h, relu'd float)
    unsigned* Ubf = (unsigned*)(aggA + n32);      // NPAD*16 (bf16-packed U)
    float* Vbuf = (float*)(Ubf + (size_t)NPAD * 16);  // n32
    unsigned* WbtG = (unsigned*)(Vbuf + n32);         // 1024 dw (2 layers x 512)

    const int NBn = (N + BS - 1) / BS;

    // fused: hist | prep1 | Wbt pack (mutually independent)
    setup_kernel<<<NB1 + NBn + 1, BS, 0, stream>>>(ei, E, NRP, blockHist, pos, W1, b1, Ubf,
                                                   Vbuf, N, NB1, NBn, W2, W4, WbtG);
    off_scan_kernel<<<(NRP * 64 + 511) / 512, 512, 0, stream>>>(blockHist, NB1, NRP, off,
                                                                total);
    range_scan_kernel<<<1, 1024, 0, stream>>>(total, NRP, rangeBase);
    bucket_scatter_kernel<<<NB1, BS, 0, stream>>>(ei, E, NRP, off, rangeBase, sedgeB);

    // --- layer 1 ---
    edge_range_kernel<<<NR, EBS, 0, stream>>>(Ubf, (const float4*)Vbuf, sedgeB, rangeBase,
                                              total, WbtG, b2, aggA, N);
    // --- layer 2 ---
    prep2_kernel<<<NBn, BS, 0, stream>>>(pos, aggA, W3, b3, Ubf, Vbuf, N);
    edge_range_kernel<<<NR, EBS, 0, stream>>>(Ubf, (const float4*)Vbuf, sedgeB, rangeBase,
                                              total, WbtG + 512, b4, (float*)d_out, N);
}

// Round 7
// 210.992 us; speedup vs baseline: 1.9573x; 1.0079x over previous
//
#include <hip/hip_runtime.h>
#include <hip/hip_bf16.h>
#include <stdint.h>

// PointNet EdgeConv, 2 layers. Round 21.
// R15: fused setup; 512-edge edge_seg blocks.                  230 us
// R17: range-bucket edge kernel (4 kernels deleted).           252 us
// R18: launch_bounds(1024,8) -> VGPR spill disaster.           413 us
// R19: spill fix + V-in-LDS + tail skip + desc prefetch.       215 us
// R20: u32-packed descriptors, linear desc loads via shfl.     213 us <- best
// R21: prep2 fused into layer-1 edge_range epilogue. Each block owns its
//      128 nodes' final h in aggL -> compute layer-2 U/V in-block
//      (4 thr/node, 8 ch each, same v2f/fma order as prep2 = bit-identical),
//      write to SEPARATE Ubf2/Vbuf2 (other blocks still read layer-1 Ubf).
//      Deletes prep2 launch + aggA global round-trip (25.6 MB).

#define BS 256
#define EBS 512        // edge kernel block size / chunk (512 edges)
#define K1_EDGES 4096  // edges staged per block in scatter pass

typedef float v2f __attribute__((ext_vector_type(2)));
typedef __attribute__((ext_vector_type(8))) short bf16x8;
typedef __attribute__((ext_vector_type(16))) float f32x16;
typedef __bf16 bf16v2 __attribute__((ext_vector_type(2)));

__device__ __forceinline__ unsigned ordenc(float f) {
    unsigned u = __float_as_uint(f);
    return (u & 0x80000000u) ? ~u : (u | 0x80000000u);
}
__device__ __forceinline__ float orddec(unsigned o) {
    unsigned u = (o & 0x80000000u) ? (o ^ 0x80000000u) : ~o;
    return __uint_as_float(u);
}
#define ORD_NEG_INF 0x007FFFFFu  // ordenc(-inf)
#define SRC_MASK 0xFFFFFu        // 20-bit src field (N < 1M)

// two f32 -> packed bf16 pair (RNE) via v_cvt_pk_bf16_f32; x -> low half
__device__ __forceinline__ unsigned cvt2(float x, float y) {
    v2f v = {x, y};
    bf16v2 b = __builtin_convertvector(v, bf16v2);
    return __builtin_bit_cast(unsigned, b);
}
__device__ __forceinline__ float bflo(unsigned u) { return __uint_as_float(u << 16); }
__device__ __forceinline__ float bfhi(unsigned u) { return __uint_as_float(u & 0xFFFF0000u); }

// build 8 channels of h = relu(bf16(U) - V) as 4 packed bf16 pairs
__device__ __forceinline__ uint4 mk_frag(uint4 ua, float4 v0, float4 v1) {
    uint4 o;
    o.x = cvt2(fmaxf(bflo(ua.x) - v0.x, 0.0f), fmaxf(bfhi(ua.x) - v0.y, 0.0f));
    o.y = cvt2(fmaxf(bflo(ua.y) - v0.z, 0.0f), fmaxf(bfhi(ua.y) - v0.w, 0.0f));
    o.z = cvt2(fmaxf(bflo(ua.z) - v1.x, 0.0f), fmaxf(bfhi(ua.z) - v1.y, 0.0f));
    o.w = cvt2(fmaxf(bflo(ua.w) - v1.z, 0.0f), fmaxf(bfhi(ua.w) - v1.w, 0.0f));
    return o;
}

// ---------------- fused setup: range-hist | prep1 | Wbt pack ----------------
__global__ __launch_bounds__(BS) void setup_kernel(
    const int* __restrict__ ei, int E, int NRP, int* __restrict__ blockHist,
    const float* __restrict__ pos, const float* __restrict__ Wa, const float* __restrict__ ba,
    unsigned* __restrict__ Ubf, float* __restrict__ V, int N, int NB1, int NBn,
    const float* __restrict__ Wb2, const float* __restrict__ Wb4,
    unsigned* __restrict__ WbtG) {
    __shared__ int hist[1024];
    const int tid = threadIdx.x;
    const int b = blockIdx.x;
    if (b < NB1) {
        for (int r = tid; r < 1024; r += BS) hist[r] = 0;
        __syncthreads();
        const int base = b * K1_EDGES;
        const int M = min(K1_EDGES, E - base);
        for (int i = tid; i < M; i += BS) atomicAdd(&hist[ei[E + base + i] >> 7], 1);
        __syncthreads();
        for (int r = tid; r < NRP; r += BS) blockHist[b * NRP + r] = hist[r];
    } else if (b < NB1 + NBn) {
        const int n = (b - NB1) * BS + tid;
        if (n >= N) return;
        const float p[3] = {pos[3 * n], pos[3 * n + 1], pos[3 * n + 2]};
        v2f u[16], v[16];
#pragma unroll
        for (int g = 0; g < 16; ++g) {
            u[g] = *reinterpret_cast<const v2f*>(&ba[g * 2]);
            v2f z = {0.0f, 0.0f};
            v[g] = z;
        }
#pragma unroll
        for (int i = 0; i < 3; ++i) {
            const v2f f = {p[i], p[i]};
#pragma unroll
            for (int g = 0; g < 16; ++g) {
                const v2f wA = *reinterpret_cast<const v2f*>(&Wa[i * 32 + g * 2]);
                const v2f wB = *reinterpret_cast<const v2f*>(&Wa[(i + 3) * 32 + g * 2]);
                u[g] = __builtin_elementwise_fma(f, wA + wB, u[g]);
                v[g] = __builtin_elementwise_fma(f, wB, v[g]);
            }
        }
        uint4* Up = reinterpret_cast<uint4*>(Ubf + (size_t)n * 16);
        float4* Vp = reinterpret_cast<float4*>(V + (size_t)n * 32);
#pragma unroll
        for (int q = 0; q < 4; ++q) {
            uint4 o;
            o.x = cvt2(u[4 * q + 0].x, u[4 * q + 0].y);
            o.y = cvt2(u[4 * q + 1].x, u[4 * q + 1].y);
            o.z = cvt2(u[4 * q + 2].x, u[4 * q + 2].y);
            o.w = cvt2(u[4 * q + 3].x, u[4 * q + 3].y);
            Up[q] = o;
        }
#pragma unroll
        for (int q = 0; q < 8; ++q)
            Vp[q] = make_float4(v[2 * q].x, v[2 * q].y, v[2 * q + 1].x, v[2 * q + 1].y);
    } else {
        // pack per-lane B fragments (bf16 pairs) for both layers: 2 x 512 dw
        if (tid < 128) {
            const int layer = tid >> 6;
            const int t = tid & 63;
            const int lnp = t & 31;
            const int hp = t >> 5;
            const float* Wb = layer ? Wb4 : Wb2;
            unsigned* dst = WbtG + layer * 512 + t * 8;
#pragma unroll
            for (int q = 0; q < 4; ++q) {
                const int p = 4 * hp + q;
                dst[q] = cvt2(Wb[(2 * p) * 32 + lnp], Wb[(2 * p + 1) * 32 + lnp]);
                dst[4 + q] = cvt2(Wb[(2 * p + 16) * 32 + lnp], Wb[(2 * p + 17) * 32 + lnp]);
            }
        }
    }
}

// ---------------- pass 2a: per-(block,range) LOCAL prefixes + range totals --
__global__ __launch_bounds__(512) void off_scan_kernel(const int* __restrict__ blockHist,
                                                       int NB1, int NRP,
                                                       int* __restrict__ off,
                                                       int* __restrict__ total) {
    const int r = (blockIdx.x * 512 + threadIdx.x) >> 6;
    const int lane = threadIdx.x & 63;
    if (r >= NRP) return;
    int carry = 0;
    const int chunks = (NB1 + 63) / 64;
    for (int c = 0; c < chunks; ++c) {
        const int b = c * 64 + lane;
        const int v = (b < NB1) ? blockHist[b * NRP + r] : 0;
        int x = v;
#pragma unroll
        for (int d = 1; d < 64; d <<= 1) {
            int y = __shfl_up(x, d, 64);
            if (lane >= d) x += y;
        }
        if (b < NB1) off[b * NRP + r] = carry + (x - v);
        carry += __shfl(x, 63, 64);
    }
    if (lane == 0) total[r] = carry;
}

// ---------------- pass 2b: exclusive scan of totals -> rangeBase ------------
__global__ __launch_bounds__(1024) void range_scan_kernel(const int* __restrict__ total,
                                                          int NRP, int* __restrict__ rangeBase) {
    __shared__ int s[1024];
    const int t = threadIdx.x;
    const int v = (t < NRP) ? total[t] : 0;
    s[t] = v;
    __syncthreads();
    for (int off = 1; off < 1024; off <<= 1) {
        int add = (t >= off) ? s[t - off] : 0;
        __syncthreads();
        s[t] += add;
        __syncthreads();
    }
    if (t < NRP) rangeBase[t] = s[t] - v;
}

// ---------------- pass 1b: LDS-ranked scatter into range buckets ------------
// Stages u32-packed edges (src | dstLocal<<20) + u16 range ids.
__global__ __launch_bounds__(BS) void bucket_scatter_kernel(
    const int* __restrict__ ei, int E, int NRP, const int* __restrict__ off,
    const int* __restrict__ rangeBase, unsigned* __restrict__ sedgeB) {
    __shared__ unsigned stage[K1_EDGES];      // 16 KB
    __shared__ unsigned short rng[K1_EDGES];  // 8 KB
    __shared__ unsigned short inv[K1_EDGES];  // 8 KB
    __shared__ int hist[1024], start[1024], cursor[1024];
    __shared__ int ts[BS];
    const int tid = threadIdx.x;
    for (int r = tid; r < 1024; r += BS) hist[r] = 0;
    __syncthreads();
    const int base = blockIdx.x * K1_EDGES;
    const int M = min(K1_EDGES, E - base);
    for (int i = tid; i < M; i += BS) {
        const int src = ei[base + i];
        const int dst = ei[E + base + i];
        const int r = dst >> 7;
        stage[i] = (unsigned)src | ((unsigned)(dst & 127) << 20);
        rng[i] = (unsigned short)r;
        atomicAdd(&hist[r], 1);
    }
    __syncthreads();
    {
        const int i0 = tid * 4;
        const int l0 = hist[i0], l1 = hist[i0 + 1], l2 = hist[i0 + 2], l3 = hist[i0 + 3];
        const int tsum = l0 + l1 + l2 + l3;
        ts[tid] = tsum;
        __syncthreads();
        for (int off2 = 1; off2 < BS; off2 <<= 1) {
            int add = (tid >= off2) ? ts[tid - off2] : 0;
            __syncthreads();
            ts[tid] += add;
            __syncthreads();
        }
        const int texcl = ts[tid] - tsum;
        start[i0] = texcl;
        start[i0 + 1] = texcl + l0;
        start[i0 + 2] = texcl + l0 + l1;
        start[i0 + 3] = texcl + l0 + l1 + l2;
        cursor[i0] = start[i0];
        cursor[i0 + 1] = start[i0 + 1];
        cursor[i0 + 2] = start[i0 + 2];
        cursor[i0 + 3] = start[i0 + 3];
    }
    __syncthreads();
    for (int i = tid; i < M; i += BS) {
        const int pos = atomicAdd(&cursor[rng[i]], 1);
        inv[pos] = (unsigned short)i;
    }
    __syncthreads();
    const int* offb = off + blockIdx.x * NRP;
    for (int j = tid; j < M; j += BS) {
        const int i = inv[j];
        const int r = rng[i];
        sedgeB[rangeBase[r] + offb[r] + (j - start[r])] = stage[i];  // contiguous runs
    }
}

// ---------------- range-bucket edge kernel (8 waves / 512-edge chunks) ------
// MODE 0: final layer — decode aggL, relu, write float out.
// MODE 1: fused prep — compute layer-2 U/V for this block's 128 nodes
//         (4 thr/node, 8 ch each; same v2f/fma order as old prep2 ->
//         bit-identical) and write Ubf2/Vbuf2.
template <int MODE>
__global__ __launch_bounds__(EBS, 6) void edge_range_kernel(
    const unsigned* __restrict__ Ubf, const float4* __restrict__ V,
    const unsigned* __restrict__ sedgeB, const int* __restrict__ rangeBase,
    const int* __restrict__ total, const unsigned* __restrict__ WbtG,
    const float* __restrict__ bb, const float* __restrict__ pos,
    const float* __restrict__ Wa2, const float* __restrict__ ba2,
    unsigned* __restrict__ Ubf2, float* __restrict__ Vbuf2,
    float* __restrict__ out, int N) {
    __shared__ unsigned aggL[4096];              // [128 dst][32 ch], 16 KB
    __shared__ __align__(16) float4 vlds[1152];  // [128 rows][9 f4] (8 used), 18 KB

    const int tid = threadIdx.x;
    const int r = blockIdx.x;
    const int base = rangeBase[r];
    const int M = total[r];
    const int last = M - 1;

    const int l = tid & 63;
    const int w = tid >> 6;  // 0..7: wave w owns chunk edges [64w, 64w+64)
    const int half = l >> 5;
    const int ln = l & 31;

#pragma unroll
    for (int i = 0; i < 8; ++i) aggL[tid + i * EBS] = ORD_NEG_INF;

    // stage V rows [128r, 128r+128): coalesced, padded stride 9
    {
        const float4* Vg = V + ((size_t)r << 10);        // row 128r, 8 f4/row
        const int vmax = min(1024, (N - (r << 7)) * 8);  // clamp at N
        for (int j = tid; j < vmax; j += EBS) vlds[(j >> 3) * 9 + (j & 7)] = Vg[j];
    }

    // B fragments: precomputed per-lane packed bf16 (L1-hot, 2 loads)
    const uint4 bu0 = *reinterpret_cast<const uint4*>(WbtG + l * 8);
    const uint4 bu1 = *reinterpret_cast<const uint4*>(WbtG + l * 8 + 4);
    const float bbn = bb[ln];
    __syncthreads();  // aggL init + V stage visible

    const int nch = (M + EBS - 1) >> 9;
    unsigned pk = 0;
    if (64 * w < M) pk = sedgeB[base + min(64 * w + l, last)];  // chunk-0 descs
    for (int c = 0; c < nch; ++c) {
        // prefetch next chunk's descriptors (wave-uniform participation)
        unsigned npk = 0;
        const int ncb = (c + 1) << 9;
        const bool nextAct = (c + 1 < nch) && (ncb + 64 * w < M);
        if (nextAct) npk = sedgeB[base + min(ncb + 64 * w + l, last)];
        if ((c << 9) + 64 * w < M) {  // this wave active this chunk
            const unsigned pkA = __shfl(pk, ln, 64);       // edge cb+64w+ln
            const unsigned pkB = __shfl(pk, 32 + ln, 64);  // edge cb+64w+32+ln
            uint4 au00, au01, au10, au11;
            {
                const uint4* Up = reinterpret_cast<const uint4*>(Ubf + (size_t)(pkA & SRC_MASK) * 16);
                const float4* Vr = &vlds[(pkA >> 20) * 9];
                au00 = mk_frag(Up[half], Vr[2 * half], Vr[2 * half + 1]);
                au01 = mk_frag(Up[2 + half], Vr[4 + 2 * half], Vr[5 + 2 * half]);
            }
            {
                const uint4* Up = reinterpret_cast<const uint4*>(Ubf + (size_t)(pkB & SRC_MASK) * 16);
                const float4* Vr = &vlds[(pkB >> 20) * 9];
                au10 = mk_frag(Up[half], Vr[2 * half], Vr[2 * half + 1]);
                au11 = mk_frag(Up[2 + half], Vr[4 + 2 * half], Vr[5 + 2 * half]);
            }

            f32x16 c0, c1;
#pragma unroll
            for (int i = 0; i < 16; ++i) {
                c0[i] = bbn;
                c1[i] = bbn;
            }
            c0 = __builtin_amdgcn_mfma_f32_32x32x16_bf16(
                __builtin_bit_cast(bf16x8, au00), __builtin_bit_cast(bf16x8, bu0), c0, 0, 0, 0);
            c0 = __builtin_amdgcn_mfma_f32_32x32x16_bf16(
                __builtin_bit_cast(bf16x8, au01), __builtin_bit_cast(bf16x8, bu1), c0, 0, 0, 0);
            c1 = __builtin_amdgcn_mfma_f32_32x32x16_bf16(
                __builtin_bit_cast(bf16x8, au10), __builtin_bit_cast(bf16x8, bu0), c1, 0, 0, 0);
            c1 = __builtin_amdgcn_mfma_f32_32x32x16_bf16(
                __builtin_bit_cast(bf16x8, au11), __builtin_bit_cast(bf16x8, bu1), c1, 0, 0, 0);

            // scatter-max: C row rr <-> edge offset eo = (rr&3)+8(rr>>2)+4h;
            // edge cb+64w+eo held by lane eo (c0) / lane 32+eo (c1).
            // aggL addr (dl<<5)|ln: lanes of a half hit distinct banks.
#pragma unroll
            for (int rr = 0; rr < 16; ++rr) {
                const int eo = (rr & 3) + 8 * (rr >> 2) + 4 * half;
                const int d0 = __shfl(pk, eo, 64) >> 20;
                const int d1 = __shfl(pk, 32 + eo, 64) >> 20;
                atomicMax(&aggL[(d0 << 5) | ln], ordenc(c0[rr]));
                atomicMax(&aggL[(d1 << 5) | ln], ordenc(c1[rr]));
            }
        }
        pk = npk;  // garbage if !nextAct, but then unused next iter
    }
    __syncthreads();

    if (MODE == 0) {
        // final writeout: 4096 values, 8 per thread, decode + relu -> float
        const int idx = tid * 8;
        const int node = (r << 7) + (idx >> 5);
        if (node < N) {
            float4 o0, o1;
            o0.x = fmaxf(orddec(aggL[idx + 0]), 0.0f);
            o0.y = fmaxf(orddec(aggL[idx + 1]), 0.0f);
            o0.z = fmaxf(orddec(aggL[idx + 2]), 0.0f);
            o0.w = fmaxf(orddec(aggL[idx + 3]), 0.0f);
            o1.x = fmaxf(orddec(aggL[idx + 4]), 0.0f);
            o1.y = fmaxf(orddec(aggL[idx + 5]), 0.0f);
            o1.z = fmaxf(orddec(aggL[idx + 6]), 0.0f);
            o1.w = fmaxf(orddec(aggL[idx + 7]), 0.0f);
            float4* op = reinterpret_cast<float4*>(out + (size_t)node * 32 + (idx & 31));
            op[0] = o0;
            op[1] = o1;
        }
    } else {
        // fused layer-2 prep: 4 threads per node, 8 channels each.
        const int node_l = tid >> 2;  // 0..127
        const int qq = tid & 3;       // channel group [8qq, 8qq+8)
        const int node = (r << 7) + node_l;
        if (node < N) {
            const unsigned* row = &aggL[node_l << 5];
            float h[32];
#pragma unroll
            for (int i = 0; i < 32; ++i) h[i] = fmaxf(orddec(row[i]), 0.0f);
            const float pp[3] = {pos[3 * node], pos[3 * node + 1], pos[3 * node + 2]};
            v2f u[4], v[4];
#pragma unroll
            for (int g = 0; g < 4; ++g) {
                u[g] = *reinterpret_cast<const v2f*>(&ba2[8 * qq + 2 * g]);
                v2f z = {0.0f, 0.0f};
                v[g] = z;
            }
#pragma unroll
            for (int i = 0; i < 32; ++i) {
                const v2f f = {h[i], h[i]};
#pragma unroll
                for (int g = 0; g < 4; ++g) {
                    const v2f wv =
                        *reinterpret_cast<const v2f*>(&Wa2[i * 32 + 8 * qq + 2 * g]);
                    u[g] = __builtin_elementwise_fma(f, wv, u[g]);
                }
            }
#pragma unroll
            for (int i = 0; i < 3; ++i) {
                const v2f f = {pp[i], pp[i]};
#pragma unroll
                for (int g = 0; g < 4; ++g) {
                    const v2f wv =
                        *reinterpret_cast<const v2f*>(&Wa2[(32 + i) * 32 + 8 * qq + 2 * g]);
                    u[g] = __builtin_elementwise_fma(f, wv, u[g]);
                    v[g] = __builtin_elementwise_fma(f, wv, v[g]);
                }
            }
            uint4 o;
            o.x = cvt2(u[0].x, u[0].y);
            o.y = cvt2(u[1].x, u[1].y);
            o.z = cvt2(u[2].x, u[2].y);
            o.w = cvt2(u[3].x, u[3].y);
            reinterpret_cast<uint4*>(Ubf2 + (size_t)node * 16)[qq] = o;
            float4* Vp = reinterpret_cast<float4*>(Vbuf2 + (size_t)node * 32 + 8 * qq);
            Vp[0] = make_float4(v[0].x, v[0].y, v[1].x, v[1].y);
            Vp[1] = make_float4(v[2].x, v[2].y, v[3].x, v[3].y);
        }
    }
}

extern "C" void kernel_launch(void* const* d_in, const int* in_sizes, int n_in,
                              void* d_out, int out_size, void* d_ws, size_t ws_size,
                              hipStream_t stream) {
    const float* pos = (const float*)d_in[0];
    const int* ei = (const int*)d_in[1];
    const float* W1 = (const float*)d_in[3];
    const float* b1 = (const float*)d_in[4];
    const float* W2 = (const float*)d_in[5];
    const float* b2 = (const float*)d_in[6];
    const float* W3 = (const float*)d_in[7];
    const float* b3 = (const float*)d_in[8];
    const float* W4 = (const float*)d_in[9];
    const float* b4 = (const float*)d_in[10];

    const int E = in_sizes[1] / 2;
    const int N = in_sizes[0] / 3;
    const int n32 = N * 32;
    const int NPAD = ((N + BS - 1) / BS) * BS;
    const int NR = (N + 127) / 128;         // ranges of 128 dsts
    const int NRP = ((NR + 15) / 16) * 16;  // padded (<= 1024)
    const int NB1 = (E + K1_EDGES - 1) / K1_EDGES;
    const int BH = NB1 * NRP;

    int* blockHist = (int*)d_ws;                      // BH
    int* off = blockHist + BH;                        // BH
    int* total = off + BH;                            // NRP
    int* rangeBase = total + NRP;                     // NRP
    unsigned* sedgeB = (unsigned*)(rangeBase + NRP);  // E (u32-packed edges)
    unsigned* Ubf = (unsigned*)(sedgeB + E);          // NPAD*16 (layer-1 U)
    float* Vbuf = (float*)(Ubf + (size_t)NPAD * 16);  // n32 (layer-1 V)
    unsigned* Ubf2 = (unsigned*)(Vbuf + n32);         // NPAD*16 (layer-2 U)
    float* Vbuf2 = (float*)(Ubf2 + (size_t)NPAD * 16);  // n32 (layer-2 V)
    unsigned* WbtG = (unsigned*)(Vbuf2 + n32);        // 1024 dw (2 layers x 512)

    const int NBn = (N + BS - 1) / BS;

    // fused: hist | prep1 | Wbt pack (mutually independent)
    setup_kernel<<<NB1 + NBn + 1, BS, 0, stream>>>(ei, E, NRP, blockHist, pos, W1, b1, Ubf,
                                                   Vbuf, N, NB1, NBn, W2, W4, WbtG);
    off_scan_kernel<<<(NRP * 64 + 511) / 512, 512, 0, stream>>>(blockHist, NB1, NRP, off,
                                                                total);
    range_scan_kernel<<<1, 1024, 0, stream>>>(total, NRP, rangeBase);
    bucket_scatter_kernel<<<NB1, BS, 0, stream>>>(ei, E, NRP, off, rangeBase, sedgeB);

    // --- layer 1 (fused layer-2 prep in epilogue) ---
    edge_range_kernel<1><<<NR, EBS, 0, stream>>>(Ubf, (const float4*)Vbuf, sedgeB, rangeBase,
                                                 total, WbtG, b2, pos, W3, b3, Ubf2, Vbuf2,
                                                 nullptr, N);
    // --- layer 2 (final) ---
    edge_range_kernel<0><<<NR, EBS, 0, stream>>>(Ubf2, (const float4*)Vbuf2, sedgeB,
                                                 rangeBase, total, WbtG + 512, b4, nullptr,
                                                 nullptr, nullptr, nullptr, nullptr,
                                                 (float*)d_out, N);
}